// Round 1
// baseline (4270.502 us; speedup 1.0000x reference)
//
#include <hip/hip_runtime.h>
#include <math.h>

// ---------------------------------------------------------------------------
// 2-layer GCN:  out = gcn(relu(gcn(x, W1, b1)), W2, b2)
// gcn(x,W,b)[c] = dinv[c] * ( y[c] + sum_{edges r->c} y[r] ) + b
//   where y[r] = dinv[r] * (x[r] @ W),  dinv = rsqrt(1 + indeg)
// ---------------------------------------------------------------------------

__global__ void k_deg_init(float* __restrict__ deg, int N) {
    int i = blockIdx.x * blockDim.x + threadIdx.x;
    if (i < N) deg[i] = 1.0f;  // self loop
}

__global__ void k_deg_count(const int* __restrict__ col, int E, float* __restrict__ deg) {
    int i = blockIdx.x * blockDim.x + threadIdx.x;
    int stride = gridDim.x * blockDim.x;
    for (int e = i; e < E; e += stride) atomicAdd(&deg[col[e]], 1.0f);
}

__global__ void k_dinv(float* __restrict__ deg, int N) {
    int i = blockIdx.x * blockDim.x + threadIdx.x;
    if (i < N) {
        float d = deg[i];
        deg[i] = (d > 0.0f) ? 1.0f / sqrtf(d) : 0.0f;
    }
}

// Y[m][n] = dinv[m] * sum_k X[m][k] * W[k][n]
// 64x64 tile, BK=16, 256 threads, 4x4 per thread. K % 16 == 0, NC % 64 == 0.
__global__ __launch_bounds__(256) void k_gemm_scale(
    const float* __restrict__ X, const float* __restrict__ W,
    const float* __restrict__ dinv, float* __restrict__ Y,
    int M, int K, int NC)
{
    __shared__ float As[16][65];  // [k][m], padded
    __shared__ float Bs[16][68];  // [k][n], padded (row stride 272B, 16B-aligned)

    const int bm = blockIdx.x * 64;
    const int bn = blockIdx.y * 64;
    const int tid = threadIdx.x;
    const int tx = tid & 15, ty = tid >> 4;

    float acc[4][4] = {};

    const int lam = tid >> 2;         // 0..63 : m within tile (A loader)
    const int lak = (tid & 3) * 4;    // 0,4,8,12 : k within tile
    const int lbr = (tid * 4) >> 6;   // 0..15 : k within tile (B loader)
    const int lbc = (tid * 4) & 63;   // col within tile

    for (int k0 = 0; k0 < K; k0 += 16) {
        float4 av = make_float4(0.f, 0.f, 0.f, 0.f);
        int gm = bm + lam;
        if (gm < M)
            av = *reinterpret_cast<const float4*>(&X[(long)gm * K + k0 + lak]);
        As[lak + 0][lam] = av.x;
        As[lak + 1][lam] = av.y;
        As[lak + 2][lam] = av.z;
        As[lak + 3][lam] = av.w;

        float4 bv = *reinterpret_cast<const float4*>(&W[(long)(k0 + lbr) * NC + bn + lbc]);
        *reinterpret_cast<float4*>(&Bs[lbr][lbc]) = bv;

        __syncthreads();
        #pragma unroll
        for (int k = 0; k < 16; k++) {
            float a[4], b[4];
            #pragma unroll
            for (int i = 0; i < 4; i++) a[i] = As[k][ty * 4 + i];
            #pragma unroll
            for (int j = 0; j < 4; j++) b[j] = Bs[k][tx * 4 + j];
            #pragma unroll
            for (int i = 0; i < 4; i++)
                #pragma unroll
                for (int j = 0; j < 4; j++) acc[i][j] += a[i] * b[j];
        }
        __syncthreads();
    }

    #pragma unroll
    for (int i = 0; i < 4; i++) {
        int gm = bm + ty * 4 + i;
        if (gm >= M) break;
        float s = dinv[gm];
        float4 v = make_float4(acc[i][0] * s, acc[i][1] * s, acc[i][2] * s, acc[i][3] * s);
        *reinterpret_cast<float4*>(&Y[(long)gm * NC + bn + tx * 4]) = v;
    }
}

__global__ void k_copy4(const float* __restrict__ src, float* __restrict__ dst, long n4) {
    long i = (long)blockIdx.x * blockDim.x + threadIdx.x;
    long stride = (long)gridDim.x * blockDim.x;
    for (; i < n4; i += stride)
        reinterpret_cast<float4*>(dst)[i] = reinterpret_cast<const float4*>(src)[i];
}

// acc[col[e]][:] += Y[row[e]][:]   (F = 4 << logq floats per row)
__global__ void k_scatter(const int* __restrict__ row, const int* __restrict__ col,
                          int E, const float* __restrict__ Y, float* __restrict__ acc,
                          int logq)
{
    const int Q = 1 << logq;
    long total = (long)E << logq;
    long i = (long)blockIdx.x * blockDim.x + threadIdx.x;
    long stride = (long)gridDim.x * blockDim.x;
    for (; i < total; i += stride) {
        int e = (int)(i >> logq);
        int q = (int)(i & (Q - 1));
        int r = row[e], c = col[e];
        float4 v = reinterpret_cast<const float4*>(Y)[((long)r << logq) + q];
        float* dst = acc + ((((long)c << logq) + q) << 2);
        atomicAdd(dst + 0, v.x);
        atomicAdd(dst + 1, v.y);
        atomicAdd(dst + 2, v.z);
        atomicAdd(dst + 3, v.w);
    }
}

// out[i] = act( dinv[node] * acc[i] + bias[f] ), vectorized by float4
__global__ void k_finalize4(const float* __restrict__ acc, const float* __restrict__ dinv,
                            const float* __restrict__ bias, long n4, int logq,
                            int do_relu, float* __restrict__ out)
{
    const int Q = 1 << logq;
    long i = (long)blockIdx.x * blockDim.x + threadIdx.x;
    long stride = (long)gridDim.x * blockDim.x;
    for (; i < n4; i += stride) {
        long node = i >> logq;
        int q = (int)(i & (Q - 1));
        float s = dinv[node];
        float4 a = reinterpret_cast<const float4*>(acc)[i];
        float4 b = reinterpret_cast<const float4*>(bias)[q];
        float4 v = make_float4(fmaf(s, a.x, b.x), fmaf(s, a.y, b.y),
                               fmaf(s, a.z, b.z), fmaf(s, a.w, b.w));
        if (do_relu) {
            v.x = v.x > 0.f ? v.x : 0.f;
            v.y = v.y > 0.f ? v.y : 0.f;
            v.z = v.z > 0.f ? v.z : 0.f;
            v.w = v.w > 0.f ? v.w : 0.f;
        }
        reinterpret_cast<float4*>(out)[i] = v;
    }
}

extern "C" void kernel_launch(void* const* d_in, const int* in_sizes, int n_in,
                              void* d_out, int out_size, void* d_ws, size_t ws_size,
                              hipStream_t stream)
{
    const float* x   = (const float*)d_in[0];
    const int*   ei  = (const int*)d_in[1];   // [2][E] int32 per harness convention
    const float* W1  = (const float*)d_in[2];
    const float* b1  = (const float*)d_in[3];
    const float* W2  = (const float*)d_in[4];
    const float* b2  = (const float*)d_in[5];

    const int nhid  = in_sizes[3];            // 256
    const int nfeat = in_sizes[5];            // 128
    const int N     = in_sizes[0] / nhid;     // 50000
    const int E     = in_sizes[1] / 2;        // 800000

    const int* row = ei;        // source
    const int* col = ei + E;    // target

    // log2 of float4-chunks per row
    int logq1 = 0; while ((4 << logq1) < nhid)  logq1++;   // 6 for 256
    int logq2 = 0; while ((4 << logq2) < nfeat) logq2++;   // 5 for 128

    // workspace carve-up
    size_t cur = 0;
    auto alloc = [&](size_t bytes) {
        void* p = (char*)d_ws + cur;
        cur += (bytes + 255) & ~(size_t)255;
        return p;
    };
    float* dinv = (float*)alloc((size_t)N * 4);
    float* y1   = (float*)alloc((size_t)N * nhid * 4);    // dinv * (x@W1)
    float* acc1 = (float*)alloc((size_t)N * nhid * 4);    // aggregation buf -> h (in place)
    float* y2   = (float*)alloc((size_t)N * nfeat * 4);   // dinv * (h@W2)
    float* out  = (float*)d_out;                          // aggregation buf 2 -> out (in place)
    (void)ws_size; (void)n_in; (void)out_size;

    const int T = 256;

    // degrees -> dinv
    k_deg_init<<<(N + T - 1) / T, T, 0, stream>>>(dinv, N);
    k_deg_count<<<1024, T, 0, stream>>>(col, E, dinv);
    k_dinv<<<(N + T - 1) / T, T, 0, stream>>>(dinv, N);

    // ---- layer 1 ----
    {
        dim3 grid((N + 63) / 64, nhid / 64);
        k_gemm_scale<<<grid, T, 0, stream>>>(x, W1, dinv, y1, N, nhid, nhid);
    }
    long n4_1 = (long)N << logq1;
    k_copy4<<<2048, T, 0, stream>>>(y1, acc1, n4_1);                       // self-loop term
    k_scatter<<<8192, T, 0, stream>>>(row, col, E, y1, acc1, logq1);       // edges
    k_finalize4<<<2048, T, 0, stream>>>(acc1, dinv, b1, n4_1, logq1, 1, acc1);  // h = relu(...)

    // ---- layer 2 ----
    {
        dim3 grid((N + 63) / 64, nfeat / 64);
        k_gemm_scale<<<grid, T, 0, stream>>>(acc1, W2, dinv, y2, N, nhid, nfeat);
    }
    long n4_2 = (long)N << logq2;
    k_copy4<<<2048, T, 0, stream>>>(y2, out, n4_2);
    k_scatter<<<8192, T, 0, stream>>>(row, col, E, y2, out, logq2);
    k_finalize4<<<2048, T, 0, stream>>>(out, dinv, b2, n4_2, logq2, 0, out);
}

// Round 2
// 427.578 us; speedup vs baseline: 9.9876x; 9.9876x over previous
//
#include <hip/hip_runtime.h>
#include <math.h>

// ---------------------------------------------------------------------------
// 2-layer GCN:  out = gcn(relu(gcn(x, W1, b1)), W2, b2)
// gcn(x,W,b)[c] = dinv[c] * ( y[c] + sum_{edges r->c} y[r] ) + b
//   where y[r] = dinv[r] * (x[r] @ W),  dinv = rsqrt(1 + indeg)
// CSR (counting sort by target) -> gather aggregation, NO float atomics.
// ---------------------------------------------------------------------------

__global__ void k_zero_i(int* __restrict__ p, int n) {
    int i = blockIdx.x * blockDim.x + threadIdx.x;
    if (i < n) p[i] = 0;
}

__global__ void k_count(const int* __restrict__ col, int E, int* __restrict__ deg) {
    int i = blockIdx.x * blockDim.x + threadIdx.x;
    int s = gridDim.x * blockDim.x;
    for (int e = i; e < E; e += s) atomicAdd(&deg[col[e]], 1);
}

__global__ void k_dinv(const int* __restrict__ deg, float* __restrict__ dinv, int N) {
    int i = blockIdx.x * blockDim.x + threadIdx.x;
    if (i < N) dinv[i] = rsqrtf((float)(1 + deg[i]));  // +1 = self loop
}

// --- 3-phase exclusive scan of deg[N] -> rowptr[N+1] ---
__global__ __launch_bounds__(1024) void k_scan1(const int* __restrict__ deg, int N,
                                                int* __restrict__ incl, int* __restrict__ bsum) {
    __shared__ int sm[1024];
    int t = threadIdx.x;
    int i = blockIdx.x * 1024 + t;
    sm[t] = (i < N) ? deg[i] : 0;
    __syncthreads();
    for (int off = 1; off < 1024; off <<= 1) {
        int add = (t >= off) ? sm[t - off] : 0;
        __syncthreads();
        sm[t] += add;
        __syncthreads();
    }
    incl[i] = sm[t];
    if (t == 1023) bsum[blockIdx.x] = sm[t];
}

__global__ void k_scan2(const int* __restrict__ bsum, int* __restrict__ boff, int nb) {
    if (threadIdx.x == 0 && blockIdx.x == 0) {
        int run = 0;
        for (int b = 0; b < nb; b++) { boff[b] = run; run += bsum[b]; }
    }
}

__global__ void k_scan3(const int* __restrict__ incl, const int* __restrict__ boff,
                        int N, int* __restrict__ rowptr) {
    int i = blockIdx.x * blockDim.x + threadIdx.x;
    if (i < N) rowptr[i + 1] = incl[i] + boff[i >> 10];
    if (i == 0) rowptr[0] = 0;
}

__global__ void k_fill(const int* __restrict__ row, const int* __restrict__ col, int E,
                       const int* __restrict__ rowptr, int* __restrict__ cursor,
                       int* __restrict__ srcidx) {
    int i = blockIdx.x * blockDim.x + threadIdx.x;
    int s = gridDim.x * blockDim.x;
    for (int e = i; e < E; e += s) {
        int c = col[e];
        int pos = rowptr[c] + atomicAdd(&cursor[c], 1);
        srcidx[pos] = row[e];
    }
}

// Y[m][n] = dinv[m] * sum_k X[m][k] * W[k][n]
// 64x64 tile, BK=16, 256 threads, 4x4 per thread. K % 16 == 0, NC % 64 == 0.
__global__ __launch_bounds__(256) void k_gemm_scale(
    const float* __restrict__ X, const float* __restrict__ W,
    const float* __restrict__ dinv, float* __restrict__ Y,
    int M, int K, int NC)
{
    __shared__ float As[16][65];
    __shared__ float Bs[16][68];

    const int bm = blockIdx.x * 64;
    const int bn = blockIdx.y * 64;
    const int tid = threadIdx.x;
    const int tx = tid & 15, ty = tid >> 4;

    float acc[4][4] = {};

    const int lam = tid >> 2;
    const int lak = (tid & 3) * 4;
    const int lbr = (tid * 4) >> 6;
    const int lbc = (tid * 4) & 63;

    for (int k0 = 0; k0 < K; k0 += 16) {
        float4 av = make_float4(0.f, 0.f, 0.f, 0.f);
        int gm = bm + lam;
        if (gm < M)
            av = *reinterpret_cast<const float4*>(&X[(long)gm * K + k0 + lak]);
        As[lak + 0][lam] = av.x;
        As[lak + 1][lam] = av.y;
        As[lak + 2][lam] = av.z;
        As[lak + 3][lam] = av.w;

        float4 bv = *reinterpret_cast<const float4*>(&W[(long)(k0 + lbr) * NC + bn + lbc]);
        *reinterpret_cast<float4*>(&Bs[lbr][lbc]) = bv;

        __syncthreads();
        #pragma unroll
        for (int k = 0; k < 16; k++) {
            float a[4], b[4];
            #pragma unroll
            for (int i = 0; i < 4; i++) a[i] = As[k][ty * 4 + i];
            #pragma unroll
            for (int j = 0; j < 4; j++) b[j] = Bs[k][tx * 4 + j];
            #pragma unroll
            for (int i = 0; i < 4; i++)
                #pragma unroll
                for (int j = 0; j < 4; j++) acc[i][j] += a[i] * b[j];
        }
        __syncthreads();
    }

    #pragma unroll
    for (int i = 0; i < 4; i++) {
        int gm = bm + ty * 4 + i;
        if (gm >= M) break;
        float s = dinv[gm];
        float4 v = make_float4(acc[i][0] * s, acc[i][1] * s, acc[i][2] * s, acc[i][3] * s);
        *reinterpret_cast<float4*>(&Y[(long)gm * NC + bn + tx * 4]) = v;
    }
}

// out[node][:] = act( dinv[node] * (Y[node][:] + sum_{e} Y[srcidx[e]][:]) + bias )
// one thread per (node, float4-chunk); Q = 1<<logq chunks per row.
__global__ __launch_bounds__(256) void k_aggregate(
    const int* __restrict__ rowptr, const int* __restrict__ srcidx,
    const float* __restrict__ Y, const float* __restrict__ dinv,
    const float* __restrict__ bias, int N, int logq, int do_relu,
    float* __restrict__ out)
{
    long gid = (long)blockIdx.x * blockDim.x + threadIdx.x;
    int node = (int)(gid >> logq);
    if (node >= N) return;
    int q = (int)(gid & ((1 << logq) - 1));

    const float4* Y4 = reinterpret_cast<const float4*>(Y);
    long base = ((long)node << logq);

    float4 s = Y4[base + q];  // self loop term
    int beg = rowptr[node], end = rowptr[node + 1];

    // 2-edge unroll for load ILP
    int e = beg;
    for (; e + 1 < end; e += 2) {
        int r0 = srcidx[e], r1 = srcidx[e + 1];
        float4 v0 = Y4[((long)r0 << logq) + q];
        float4 v1 = Y4[((long)r1 << logq) + q];
        s.x += v0.x + v1.x;
        s.y += v0.y + v1.y;
        s.z += v0.z + v1.z;
        s.w += v0.w + v1.w;
    }
    if (e < end) {
        int r = srcidx[e];
        float4 v = Y4[((long)r << logq) + q];
        s.x += v.x; s.y += v.y; s.z += v.z; s.w += v.w;
    }

    float d = dinv[node];
    float4 b = reinterpret_cast<const float4*>(bias)[q];
    float4 o = make_float4(fmaf(d, s.x, b.x), fmaf(d, s.y, b.y),
                           fmaf(d, s.z, b.z), fmaf(d, s.w, b.w));
    if (do_relu) {
        o.x = fmaxf(o.x, 0.f);
        o.y = fmaxf(o.y, 0.f);
        o.z = fmaxf(o.z, 0.f);
        o.w = fmaxf(o.w, 0.f);
    }
    reinterpret_cast<float4*>(out)[base + q] = o;
}

extern "C" void kernel_launch(void* const* d_in, const int* in_sizes, int n_in,
                              void* d_out, int out_size, void* d_ws, size_t ws_size,
                              hipStream_t stream)
{
    const float* x   = (const float*)d_in[0];
    const int*   ei  = (const int*)d_in[1];
    const float* W1  = (const float*)d_in[2];
    const float* b1  = (const float*)d_in[3];
    const float* W2  = (const float*)d_in[4];
    const float* b2  = (const float*)d_in[5];

    const int nhid  = in_sizes[3];            // 256
    const int nfeat = in_sizes[5];            // 128
    const int N     = in_sizes[0] / nhid;     // 50000
    const int E     = in_sizes[1] / 2;        // 800000

    const int* row = ei;        // source
    const int* col = ei + E;    // target

    int logq1 = 0; while ((4 << logq1) < nhid)  logq1++;   // 6 for 256
    int logq2 = 0; while ((4 << logq2) < nfeat) logq2++;   // 5 for 128

    const int nb = (N + 1023) / 1024;

    size_t cur = 0;
    auto alloc = [&](size_t bytes) {
        void* p = (char*)d_ws + cur;
        cur += (bytes + 255) & ~(size_t)255;
        return p;
    };
    float* dinv   = (float*)alloc((size_t)N * 4);
    int*   deg_i  = (int*)alloc((size_t)N * 4);
    int*   cursor = (int*)alloc((size_t)N * 4);
    int*   rowptr = (int*)alloc((size_t)(N + 1) * 4);
    int*   incl   = (int*)alloc((size_t)nb * 1024 * 4);
    int*   bsum   = (int*)alloc((size_t)nb * 4);
    int*   boff   = (int*)alloc((size_t)nb * 4);
    int*   srcidx = (int*)alloc((size_t)E * 4);
    float* y1     = (float*)alloc((size_t)N * nhid * 4);   // also reused as y2
    float* h      = (float*)alloc((size_t)N * nhid * 4);
    float* y2     = y1;   // y1 dead after layer-1 aggregation
    float* out    = (float*)d_out;
    (void)ws_size; (void)n_in; (void)out_size;

    const int T = 256;

    // ---- CSR build + dinv ----
    k_zero_i<<<(N + T - 1) / T, T, 0, stream>>>(deg_i, N);
    k_zero_i<<<(N + T - 1) / T, T, 0, stream>>>(cursor, N);
    k_count<<<1024, T, 0, stream>>>(col, E, deg_i);
    k_dinv<<<(N + T - 1) / T, T, 0, stream>>>(deg_i, dinv, N);
    k_scan1<<<nb, 1024, 0, stream>>>(deg_i, N, incl, bsum);
    k_scan2<<<1, 64, 0, stream>>>(bsum, boff, nb);
    k_scan3<<<(N + T - 1) / T, T, 0, stream>>>(incl, boff, N, rowptr);
    k_fill<<<1024, T, 0, stream>>>(row, col, E, rowptr, cursor, srcidx);

    // ---- layer 1 ----
    {
        dim3 grid((N + 63) / 64, nhid / 64);
        k_gemm_scale<<<grid, T, 0, stream>>>(x, W1, dinv, y1, N, nhid, nhid);
    }
    {
        long total = (long)N << logq1;
        int blocks = (int)((total + T - 1) / T);
        k_aggregate<<<blocks, T, 0, stream>>>(rowptr, srcidx, y1, dinv, b1, N, logq1, 1, h);
    }

    // ---- layer 2 ----
    {
        dim3 grid((N + 63) / 64, nfeat / 64);
        k_gemm_scale<<<grid, T, 0, stream>>>(h, W2, dinv, y2, N, nhid, nfeat);
    }
    {
        long total = (long)N << logq2;
        int blocks = (int)((total + T - 1) / T);
        k_aggregate<<<blocks, T, 0, stream>>>(rowptr, srcidx, y2, dinv, b2, N, logq2, 0, out);
    }
}

// Round 3
// 290.754 us; speedup vs baseline: 14.6877x; 1.4706x over previous
//
#include <hip/hip_runtime.h>
#include <math.h>

// ---------------------------------------------------------------------------
// 2-layer GCN:  out = gcn(relu(gcn(x, W1, b1)), W2, b2)
// gcn(x,W,b)[c] = dinv[c] * ( y[c] + sum_{edges r->c} y[r] ) + b
//   where y[r] = dinv[r] * (x[r] @ W),  dinv = rsqrt(1 + indeg)
// CSR gather aggregation (no float atomics); fp16 MFMA GEMM; fp16 y gathers.
// ---------------------------------------------------------------------------

typedef _Float16 h8 __attribute__((ext_vector_type(8)));
typedef _Float16 h4 __attribute__((ext_vector_type(4)));
typedef _Float16 h2 __attribute__((ext_vector_type(2)));
typedef float    f32x4 __attribute__((ext_vector_type(4)));

template<int> struct hvec;
template<> struct hvec<2> { typedef h2 type; };
template<> struct hvec<4> { typedef h4 type; };

__global__ void k_zero_i(int* __restrict__ p, int n) {
    int i = blockIdx.x * blockDim.x + threadIdx.x;
    if (i < n) p[i] = 0;
}

__global__ void k_count(const int* __restrict__ col, int E, int* __restrict__ deg) {
    int i = blockIdx.x * blockDim.x + threadIdx.x;
    int s = gridDim.x * blockDim.x;
    for (int e = i; e < E; e += s) atomicAdd(&deg[col[e]], 1);
}

__global__ void k_dinv(const int* __restrict__ deg, float* __restrict__ dinv, int N) {
    int i = blockIdx.x * blockDim.x + threadIdx.x;
    if (i < N) dinv[i] = rsqrtf((float)(1 + deg[i]));  // +1 = self loop
}

// --- 3-phase exclusive scan of deg[N] -> rowptr[N+1] ---
__global__ __launch_bounds__(1024) void k_scan1(const int* __restrict__ deg, int N,
                                                int* __restrict__ incl, int* __restrict__ bsum) {
    __shared__ int sm[1024];
    int t = threadIdx.x;
    int i = blockIdx.x * 1024 + t;
    sm[t] = (i < N) ? deg[i] : 0;
    __syncthreads();
    for (int off = 1; off < 1024; off <<= 1) {
        int add = (t >= off) ? sm[t - off] : 0;
        __syncthreads();
        sm[t] += add;
        __syncthreads();
    }
    incl[i] = sm[t];
    if (t == 1023) bsum[blockIdx.x] = sm[t];
}

__global__ void k_scan2(const int* __restrict__ bsum, int* __restrict__ boff, int nb) {
    if (threadIdx.x == 0 && blockIdx.x == 0) {
        int run = 0;
        for (int b = 0; b < nb; b++) { boff[b] = run; run += bsum[b]; }
    }
}

__global__ void k_scan3(const int* __restrict__ incl, const int* __restrict__ boff,
                        int N, int* __restrict__ rowptr) {
    int i = blockIdx.x * blockDim.x + threadIdx.x;
    if (i < N) rowptr[i + 1] = incl[i] + boff[i >> 10];
    if (i == 0) rowptr[0] = 0;
}

__global__ void k_fill(const int* __restrict__ row, const int* __restrict__ col, int E,
                       const int* __restrict__ rowptr, int* __restrict__ cursor,
                       int* __restrict__ srcidx) {
    int i = blockIdx.x * blockDim.x + threadIdx.x;
    int s = gridDim.x * blockDim.x;
    for (int e = i; e < E; e += s) {
        int c = col[e];
        int pos = rowptr[c] + atomicAdd(&cursor[c], 1);
        srcidx[pos] = row[e];
    }
}

// fp32 -> fp16, float4-vectorized
__global__ void k_cvt_f16(const float* __restrict__ in, _Float16* __restrict__ out, long n4) {
    long i = (long)blockIdx.x * blockDim.x + threadIdx.x;
    long stride = (long)gridDim.x * blockDim.x;
    for (; i < n4; i += stride) {
        float4 v = reinterpret_cast<const float4*>(in)[i];
        h4 o;
        o[0] = (_Float16)v.x; o[1] = (_Float16)v.y;
        o[2] = (_Float16)v.z; o[3] = (_Float16)v.w;
        reinterpret_cast<h4*>(out)[i] = o;
    }
}

// Wt[n][k] = (fp16) W[k][n]
__global__ void k_transpose16(const float* __restrict__ W, _Float16* __restrict__ Wt,
                              int K, int NC) {
    int i = blockIdx.x * blockDim.x + threadIdx.x;
    if (i < K * NC) {
        int k = i / NC, n = i % NC;
        Wt[(long)n * K + k] = (_Float16)W[i];
    }
}

// Y[m][n] = fp16( dinv[m] * sum_k X[m][k] * Wt[n][k] )
// 128x64 block tile, BK=32, 256 threads = 4 waves, each wave 32x64 via
// 2x4 mfma_f32_16x16x32_f16 fragments. K % 32 == 0, NC % 64 == 0.
__global__ __launch_bounds__(256) void k_gemm16(
    const _Float16* __restrict__ X, const _Float16* __restrict__ Wt,
    const float* __restrict__ dinv, _Float16* __restrict__ Y,
    int M, int K, int NC)
{
    __shared__ _Float16 As[128][40];  // padded: row stride 80B (16B-aligned)
    __shared__ _Float16 Bs[64][40];

    const int bm = blockIdx.x * 128;
    const int bn = blockIdx.y * 64;
    const int tid = threadIdx.x;
    const int w  = tid >> 6;    // wave 0..3 -> rows [w*32, w*32+32)
    const int l  = tid & 63;
    const int lr = l & 15;      // row/col within fragment
    const int lg = l >> 4;      // k-group (8 fp16 per group)
    const int ar = tid >> 2;    // staging row 0..63
    const int ap = (tid & 3) * 8;  // staging k-offset

    f32x4 acc[2][4];
    #pragma unroll
    for (int i = 0; i < 2; i++)
        #pragma unroll
        for (int j = 0; j < 4; j++)
            acc[i][j] = (f32x4){0.f, 0.f, 0.f, 0.f};

    for (int k0 = 0; k0 < K; k0 += 32) {
        #pragma unroll
        for (int p = 0; p < 2; p++) {           // A: 128 rows in two passes
            int rowi = p * 64 + ar;
            int gm = bm + rowi; if (gm >= M) gm = M - 1;
            h8 v = *reinterpret_cast<const h8*>(&X[(long)gm * K + k0 + ap]);
            *reinterpret_cast<h8*>(&As[rowi][ap]) = v;
        }
        {                                        // B: 64 rows (cols of W)
            h8 v = *reinterpret_cast<const h8*>(&Wt[(long)(bn + ar) * K + k0 + ap]);
            *reinterpret_cast<h8*>(&Bs[ar][ap]) = v;
        }
        __syncthreads();

        h8 a[2], b[4];
        #pragma unroll
        for (int fm = 0; fm < 2; fm++)
            a[fm] = *reinterpret_cast<const h8*>(&As[w * 32 + fm * 16 + lr][lg * 8]);
        #pragma unroll
        for (int fn = 0; fn < 4; fn++)
            b[fn] = *reinterpret_cast<const h8*>(&Bs[fn * 16 + lr][lg * 8]);
        #pragma unroll
        for (int fm = 0; fm < 2; fm++)
            #pragma unroll
            for (int fn = 0; fn < 4; fn++)
                acc[fm][fn] = __builtin_amdgcn_mfma_f32_16x16x32_f16(
                    a[fm], b[fn], acc[fm][fn], 0, 0, 0);
        __syncthreads();
    }

    // epilogue: C[row=(l>>4)*4+r][col=l&15] per fragment; scale by dinv, cast fp16
    #pragma unroll
    for (int fm = 0; fm < 2; fm++) {
        #pragma unroll
        for (int r = 0; r < 4; r++) {
            int gm = bm + w * 32 + fm * 16 + lg * 4 + r;
            if (gm < M) {
                float s = dinv[gm];
                #pragma unroll
                for (int fn = 0; fn < 4; fn++)
                    Y[(long)gm * NC + bn + fn * 16 + lr] = (_Float16)(acc[fm][fn][r] * s);
            }
        }
    }
}

// out[node][:] = act( dinv[node] * (Y[node][:] + sum_e Y[srcidx[e]][:]) + bias )
// one wave per node, EPL fp16 elements per lane (F = EPL*64), fp32 accumulate.
template<int EPL, bool F16OUT, bool RELU>
__global__ __launch_bounds__(256) void k_agg16(
    const int* __restrict__ rowptr, const int* __restrict__ srcidx,
    const _Float16* __restrict__ Y, const float* __restrict__ dinv,
    const float* __restrict__ bias, int N,
    float* __restrict__ out32, _Float16* __restrict__ out16)
{
    typedef typename hvec<EPL>::type hv;
    const int F = EPL * 64;
    int node = blockIdx.x * 4 + (threadIdx.x >> 6);
    if (node >= N) return;
    int lane = threadIdx.x & 63;
    long base = (long)node * F + lane * EPL;

    float acc[EPL];
    {
        hv v = *reinterpret_cast<const hv*>(&Y[base]);  // self loop
        #pragma unroll
        for (int j = 0; j < EPL; j++) acc[j] = (float)v[j];
    }

    int beg = rowptr[node], end = rowptr[node + 1];
    int e = beg;
    for (; e + 1 < end; e += 2) {
        int r0 = srcidx[e], r1 = srcidx[e + 1];
        hv v0 = *reinterpret_cast<const hv*>(&Y[(long)r0 * F + lane * EPL]);
        hv v1 = *reinterpret_cast<const hv*>(&Y[(long)r1 * F + lane * EPL]);
        #pragma unroll
        for (int j = 0; j < EPL; j++) acc[j] += (float)v0[j] + (float)v1[j];
    }
    if (e < end) {
        int r = srcidx[e];
        hv v = *reinterpret_cast<const hv*>(&Y[(long)r * F + lane * EPL]);
        #pragma unroll
        for (int j = 0; j < EPL; j++) acc[j] += (float)v[j];
    }

    float s = dinv[node];
    if (F16OUT) {
        hv o;
        #pragma unroll
        for (int j = 0; j < EPL; j++) {
            float v = fmaf(s, acc[j], bias[lane * EPL + j]);
            if (RELU) v = fmaxf(v, 0.f);
            o[j] = (_Float16)v;
        }
        *reinterpret_cast<hv*>(&out16[base]) = o;
    } else {
        #pragma unroll
        for (int j = 0; j < EPL; j++) {
            float v = fmaf(s, acc[j], bias[lane * EPL + j]);
            if (RELU) v = fmaxf(v, 0.f);
            out32[base + j] = v;
        }
    }
}

extern "C" void kernel_launch(void* const* d_in, const int* in_sizes, int n_in,
                              void* d_out, int out_size, void* d_ws, size_t ws_size,
                              hipStream_t stream)
{
    const float* x   = (const float*)d_in[0];
    const int*   ei  = (const int*)d_in[1];
    const float* W1  = (const float*)d_in[2];
    const float* b1  = (const float*)d_in[3];
    const float* W2  = (const float*)d_in[4];
    const float* b2  = (const float*)d_in[5];

    const int nhid  = in_sizes[3];            // 256
    const int nfeat = in_sizes[5];            // 128
    const int N     = in_sizes[0] / nhid;     // 50000
    const int E     = in_sizes[1] / 2;        // 800000

    const int* row = ei;        // source
    const int* col = ei + E;    // target

    const int nb = (N + 1023) / 1024;

    size_t cur = 0;
    auto alloc = [&](size_t bytes) {
        void* p = (char*)d_ws + cur;
        cur += (bytes + 255) & ~(size_t)255;
        return p;
    };
    float*     dinv   = (float*)alloc((size_t)N * 4);
    int*       deg_i  = (int*)alloc((size_t)N * 4);
    int*       cursor = (int*)alloc((size_t)N * 4);
    int*       rowptr = (int*)alloc((size_t)(N + 1) * 4);
    int*       incl   = (int*)alloc((size_t)nb * 1024 * 4);
    int*       bsum   = (int*)alloc((size_t)nb * 4);
    int*       boff   = (int*)alloc((size_t)nb * 4);
    int*       srcidx = (int*)alloc((size_t)E * 4);
    _Float16*  x16    = (_Float16*)alloc((size_t)N * nhid * 2);
    _Float16*  wt1    = (_Float16*)alloc((size_t)nhid * nhid * 2);
    _Float16*  wt2    = (_Float16*)alloc((size_t)nhid * nfeat * 2);
    _Float16*  y16    = (_Float16*)alloc((size_t)N * nhid * 2);   // layer-1 y
    _Float16*  h16    = (_Float16*)alloc((size_t)N * nhid * 2);   // relu output
    _Float16*  y2     = (_Float16*)alloc((size_t)N * nfeat * 2);  // layer-2 y
    float*     out    = (float*)d_out;
    (void)ws_size; (void)n_in; (void)out_size;

    const int T = 256;

    // ---- CSR build + dinv ----
    k_zero_i<<<(N + T - 1) / T, T, 0, stream>>>(deg_i, N);
    k_zero_i<<<(N + T - 1) / T, T, 0, stream>>>(cursor, N);
    k_count<<<1024, T, 0, stream>>>(col, E, deg_i);
    k_dinv<<<(N + T - 1) / T, T, 0, stream>>>(deg_i, dinv, N);
    k_scan1<<<nb, 1024, 0, stream>>>(deg_i, N, incl, bsum);
    k_scan2<<<1, 64, 0, stream>>>(bsum, boff, nb);
    k_scan3<<<(N + T - 1) / T, T, 0, stream>>>(incl, boff, N, rowptr);
    k_fill<<<1024, T, 0, stream>>>(row, col, E, rowptr, cursor, srcidx);

    // ---- fp16 conversions ----
    k_cvt_f16<<<2048, T, 0, stream>>>(x, x16, (long)N * nhid / 4);
    k_transpose16<<<(nhid * nhid + T - 1) / T, T, 0, stream>>>(W1, wt1, nhid, nhid);
    k_transpose16<<<(nhid * nfeat + T - 1) / T, T, 0, stream>>>(W2, wt2, nhid, nfeat);

    // ---- layer 1 ----
    {
        dim3 grid((N + 127) / 128, nhid / 64);
        k_gemm16<<<grid, T, 0, stream>>>(x16, wt1, dinv, y16, N, nhid, nhid);
    }
    {
        int blocks = (N + 3) / 4;  // 4 nodes (waves) per block
        k_agg16<4, true, true><<<blocks, T, 0, stream>>>(
            rowptr, srcidx, y16, dinv, b1, N, nullptr, h16);
    }

    // ---- layer 2 ----
    {
        dim3 grid((N + 127) / 128, nfeat / 64);
        k_gemm16<<<grid, T, 0, stream>>>(h16, wt2, dinv, y2, N, nhid, nfeat);
    }
    {
        int blocks = (N + 3) / 4;
        k_agg16<2, false, false><<<blocks, T, 0, stream>>>(
            rowptr, srcidx, y2, dinv, b2, N, out, nullptr);
    }
}

// Round 4
// 246.019 us; speedup vs baseline: 17.3584x; 1.1818x over previous
//
#include <hip/hip_runtime.h>
#include <math.h>

// ---------------------------------------------------------------------------
// 2-layer GCN:  out = gcn(relu(gcn(x, W1, b1)), W2, b2)
// gcn(x,W,b)[c] = dinv[c] * ( y[c] + sum_{edges r->c} y[r] ) + b
//   where y[r] = dinv[r] * (x[r] @ W),  dinv = rsqrt(1 + indeg)
// CSR gather aggregation (multi-edge wave loads); fp16 MFMA GEMM (fused cvt).
// ---------------------------------------------------------------------------

typedef _Float16 h8 __attribute__((ext_vector_type(8)));
typedef float    f32x4 __attribute__((ext_vector_type(4)));

__global__ void k_zero2(int* __restrict__ a, int* __restrict__ b, int n) {
    int i = blockIdx.x * blockDim.x + threadIdx.x;
    if (i < n) { a[i] = 0; b[i] = 0; }
}

__global__ void k_count(const int* __restrict__ col, int E, int* __restrict__ deg) {
    int i = blockIdx.x * blockDim.x + threadIdx.x;
    int s = gridDim.x * blockDim.x;
    for (int e = i; e < E; e += s) atomicAdd(&deg[col[e]], 1);
}

// --- 3-phase exclusive scan of deg[N] -> rowptr[N+1] (dinv fused in ph3) ---
__global__ __launch_bounds__(1024) void k_scan1(const int* __restrict__ deg, int N,
                                                int* __restrict__ incl, int* __restrict__ bsum) {
    __shared__ int sm[1024];
    int t = threadIdx.x;
    int i = blockIdx.x * 1024 + t;
    sm[t] = (i < N) ? deg[i] : 0;
    __syncthreads();
    for (int off = 1; off < 1024; off <<= 1) {
        int add = (t >= off) ? sm[t - off] : 0;
        __syncthreads();
        sm[t] += add;
        __syncthreads();
    }
    incl[i] = sm[t];
    if (t == 1023) bsum[blockIdx.x] = sm[t];
}

__global__ void k_scan2(const int* __restrict__ bsum, int* __restrict__ boff, int nb) {
    if (threadIdx.x == 0 && blockIdx.x == 0) {
        int run = 0;
        for (int b = 0; b < nb; b++) { boff[b] = run; run += bsum[b]; }
    }
}

__global__ void k_scan3(const int* __restrict__ incl, const int* __restrict__ boff,
                        const int* __restrict__ deg, int N,
                        int* __restrict__ rowptr, float* __restrict__ dinv) {
    int i = blockIdx.x * blockDim.x + threadIdx.x;
    if (i < N) {
        rowptr[i + 1] = incl[i] + boff[i >> 10];
        dinv[i] = rsqrtf((float)(1 + deg[i]));
    }
    if (i == 0) rowptr[0] = 0;
}

__global__ void k_fill(const int* __restrict__ row, const int* __restrict__ col, int E,
                       const int* __restrict__ rowptr, int* __restrict__ cursor,
                       int* __restrict__ srcidx) {
    int i = blockIdx.x * blockDim.x + threadIdx.x;
    int s = gridDim.x * blockDim.x;
    for (int e = i; e < E; e += s) {
        int c = col[e];
        int pos = rowptr[c] + atomicAdd(&cursor[c], 1);
        srcidx[pos] = row[e];
    }
}

// both weight transposes in one launch: wt[n][k] = (fp16) W[k][n]
__global__ void k_prep_w(const float* __restrict__ W1, const float* __restrict__ W2,
                         _Float16* __restrict__ wt1, _Float16* __restrict__ wt2,
                         int K, int n1, int n2) {
    int i = blockIdx.x * blockDim.x + threadIdx.x;
    int c1 = K * n1;
    if (i < c1) {
        int k = i / n1, n = i % n1;
        wt1[(long)n * K + k] = (_Float16)W1[i];
    } else if (i < c1 + K * n2) {
        int j = i - c1;
        int k = j / n2, n = j % n2;
        wt2[(long)n * K + k] = (_Float16)W2[j];
    }
}

// Y[m][n] = fp16( dinv[m] * sum_k X[m][k] * Wt[n][k] )
// 128x128 block tile, BK=32, 4 waves (2x2), each wave 64x64 via 4x4
// mfma_f32_16x16x32_f16 fragments. A32: read X as fp32, convert in staging.
template<bool A32>
__global__ __launch_bounds__(256) void k_gemm(
    const float* __restrict__ X32, const _Float16* __restrict__ X16,
    const _Float16* __restrict__ Wt, const float* __restrict__ dinv,
    _Float16* __restrict__ Y, int M, int K, int NC)
{
    __shared__ _Float16 As[128][40];  // row stride 80B (16B-aligned)
    __shared__ _Float16 Bs[128][40];

    const int bn = blockIdx.x * 128;
    const int bm = blockIdx.y * 128;
    const int tid = threadIdx.x;
    const int w = tid >> 6, l = tid & 63;
    const int wm = (w >> 1) * 64, wn = (w & 1) * 64;
    const int lr = l & 15, lg = l >> 4;

    f32x4 acc[4][4];
    #pragma unroll
    for (int i = 0; i < 4; i++)
        #pragma unroll
        for (int j = 0; j < 4; j++)
            acc[i][j] = (f32x4){0.f, 0.f, 0.f, 0.f};

    for (int k0 = 0; k0 < K; k0 += 32) {
        if (A32) {
            #pragma unroll
            for (int p = 0; p < 2; p++) {
                int rowi = p * 64 + (tid >> 2);
                int colA = (tid & 3) * 8;
                int gm = bm + rowi; if (gm >= M) gm = M - 1;
                float4 f0 = *reinterpret_cast<const float4*>(&X32[(long)gm * K + k0 + colA]);
                float4 f1 = *reinterpret_cast<const float4*>(&X32[(long)gm * K + k0 + colA + 4]);
                h8 hv;
                hv[0] = (_Float16)f0.x; hv[1] = (_Float16)f0.y;
                hv[2] = (_Float16)f0.z; hv[3] = (_Float16)f0.w;
                hv[4] = (_Float16)f1.x; hv[5] = (_Float16)f1.y;
                hv[6] = (_Float16)f1.z; hv[7] = (_Float16)f1.w;
                *reinterpret_cast<h8*>(&As[rowi][colA]) = hv;
            }
        } else {
            int rowi = tid >> 1;
            int colA = (tid & 1) * 16;
            int gm = bm + rowi; if (gm >= M) gm = M - 1;
            *reinterpret_cast<h8*>(&As[rowi][colA]) =
                *reinterpret_cast<const h8*>(&X16[(long)gm * K + k0 + colA]);
            *reinterpret_cast<h8*>(&As[rowi][colA + 8]) =
                *reinterpret_cast<const h8*>(&X16[(long)gm * K + k0 + colA + 8]);
        }
        {
            int n = tid >> 1;
            int colB = (tid & 1) * 16;
            *reinterpret_cast<h8*>(&Bs[n][colB]) =
                *reinterpret_cast<const h8*>(&Wt[(long)(bn + n) * K + k0 + colB]);
            *reinterpret_cast<h8*>(&Bs[n][colB + 8]) =
                *reinterpret_cast<const h8*>(&Wt[(long)(bn + n) * K + k0 + colB + 8]);
        }
        __syncthreads();

        h8 a[4], b[4];
        #pragma unroll
        for (int i = 0; i < 4; i++)
            a[i] = *reinterpret_cast<const h8*>(&As[wm + i * 16 + lr][lg * 8]);
        #pragma unroll
        for (int j = 0; j < 4; j++)
            b[j] = *reinterpret_cast<const h8*>(&Bs[wn + j * 16 + lr][lg * 8]);
        #pragma unroll
        for (int i = 0; i < 4; i++)
            #pragma unroll
            for (int j = 0; j < 4; j++)
                acc[i][j] = __builtin_amdgcn_mfma_f32_16x16x32_f16(
                    a[i], b[j], acc[i][j], 0, 0, 0);
        __syncthreads();
    }

    // C layout: row = (l>>4)*4 + reg, col = l&15 (verified in earlier rounds)
    #pragma unroll
    for (int i = 0; i < 4; i++) {
        #pragma unroll
        for (int r = 0; r < 4; r++) {
            int gm = bm + wm + i * 16 + lg * 4 + r;
            if (gm < M) {
                float s = dinv[gm];
                #pragma unroll
                for (int j = 0; j < 4; j++)
                    Y[(long)gm * NC + bn + wn + j * 16 + lr] =
                        (_Float16)(acc[i][j][r] * s);
            }
        }
    }
}

// out[node][:] = act( dinv[node] * (Y[node][:] + sum_e Y[srcidx[e]][:]) + bias )
// One wave per node. LPR lanes cover a row (16B/lane); G = 64/LPR edges per
// wave-load; 2-batch unroll; __shfl_xor butterfly merges sub-groups.
template<int LPR, bool F16OUT, bool RELU>
__global__ __launch_bounds__(256) void k_agg(
    const int* __restrict__ rowptr, const int* __restrict__ srcidx,
    const _Float16* __restrict__ Y, const float* __restrict__ dinv,
    const float* __restrict__ bias, int N,
    float* __restrict__ out32, _Float16* __restrict__ out16)
{
    const int G = 64 / LPR;   // edges per batch
    const int F = LPR * 8;    // fp16 features per row
    int node = blockIdx.x * 4 + (threadIdx.x >> 6);
    if (node >= N) return;
    int lane = threadIdx.x & 63;
    int sub = lane / LPR;
    int fl  = lane % LPR;

    float acc[8];
    if (sub == 0) {  // self loop handled by subgroup 0
        h8 v = *reinterpret_cast<const h8*>(&Y[(long)node * F + fl * 8]);
        #pragma unroll
        for (int j = 0; j < 8; j++) acc[j] = (float)v[j];
    } else {
        #pragma unroll
        for (int j = 0; j < 8; j++) acc[j] = 0.f;
    }

    int beg = rowptr[node], end = rowptr[node + 1];
    int cnt = end - beg;
    int i = beg + sub;
    int full = cnt / (2 * G);
    for (int t = 0; t < full; t++) {
        int r0 = srcidx[i];
        int r1 = srcidx[i + G];
        h8 v0 = *reinterpret_cast<const h8*>(&Y[(long)r0 * F + fl * 8]);
        h8 v1 = *reinterpret_cast<const h8*>(&Y[(long)r1 * F + fl * 8]);
        #pragma unroll
        for (int j = 0; j < 8; j++) acc[j] += (float)v0[j] + (float)v1[j];
        i += 2 * G;
    }
    if (i < end) {
        int r = srcidx[i];
        h8 v = *reinterpret_cast<const h8*>(&Y[(long)r * F + fl * 8]);
        #pragma unroll
        for (int j = 0; j < 8; j++) acc[j] += (float)v[j];
    }
    if (i + G < end) {
        int r = srcidx[i + G];
        h8 v = *reinterpret_cast<const h8*>(&Y[(long)r * F + fl * 8]);
        #pragma unroll
        for (int j = 0; j < 8; j++) acc[j] += (float)v[j];
    }

    // merge sub-groups (G=2: one level; G=4: two levels)
    #pragma unroll
    for (int m = LPR; m < 64; m <<= 1)
        #pragma unroll
        for (int j = 0; j < 8; j++)
            acc[j] += __shfl_xor(acc[j], m, 64);

    float s = dinv[node];
    const float4* b4 = reinterpret_cast<const float4*>(bias) + fl * 2;
    float4 blo = b4[0], bhi = b4[1];
    float r8[8];
    r8[0] = fmaf(s, acc[0], blo.x); r8[1] = fmaf(s, acc[1], blo.y);
    r8[2] = fmaf(s, acc[2], blo.z); r8[3] = fmaf(s, acc[3], blo.w);
    r8[4] = fmaf(s, acc[4], bhi.x); r8[5] = fmaf(s, acc[5], bhi.y);
    r8[6] = fmaf(s, acc[6], bhi.z); r8[7] = fmaf(s, acc[7], bhi.w);
    if (RELU) {
        #pragma unroll
        for (int j = 0; j < 8; j++) r8[j] = fmaxf(r8[j], 0.f);
    }

    long base = (long)node * F + fl * 8;
    if (F16OUT) {
        if (sub == 0) {
            h8 o;
            #pragma unroll
            for (int j = 0; j < 8; j++) o[j] = (_Float16)r8[j];
            *reinterpret_cast<h8*>(&out16[base]) = o;
        }
    } else {
        if (sub == 0) {
            *reinterpret_cast<float4*>(&out32[base]) =
                make_float4(r8[0], r8[1], r8[2], r8[3]);
        } else if (sub == 1) {
            *reinterpret_cast<float4*>(&out32[base + 4]) =
                make_float4(r8[4], r8[5], r8[6], r8[7]);
        }
    }
}

extern "C" void kernel_launch(void* const* d_in, const int* in_sizes, int n_in,
                              void* d_out, int out_size, void* d_ws, size_t ws_size,
                              hipStream_t stream)
{
    const float* x   = (const float*)d_in[0];
    const int*   ei  = (const int*)d_in[1];
    const float* W1  = (const float*)d_in[2];
    const float* b1  = (const float*)d_in[3];
    const float* W2  = (const float*)d_in[4];
    const float* b2  = (const float*)d_in[5];

    const int nhid  = in_sizes[3];            // 256
    const int nfeat = in_sizes[5];            // 128
    const int N     = in_sizes[0] / nhid;     // 50000
    const int E     = in_sizes[1] / 2;        // 800000

    const int* row = ei;        // source
    const int* col = ei + E;    // target

    const int nb = (N + 1023) / 1024;

    size_t cur = 0;
    auto alloc = [&](size_t bytes) {
        void* p = (char*)d_ws + cur;
        cur += (bytes + 255) & ~(size_t)255;
        return p;
    };
    float*     dinv   = (float*)alloc((size_t)N * 4);
    int*       deg_i  = (int*)alloc((size_t)N * 4);
    int*       cursor = (int*)alloc((size_t)N * 4);
    int*       rowptr = (int*)alloc((size_t)(N + 1) * 4);
    int*       incl   = (int*)alloc((size_t)nb * 1024 * 4);
    int*       bsum   = (int*)alloc((size_t)nb * 4);
    int*       boff   = (int*)alloc((size_t)nb * 4);
    int*       srcidx = (int*)alloc((size_t)E * 4);
    _Float16*  wt1    = (_Float16*)alloc((size_t)nhid * nhid * 2);
    _Float16*  wt2    = (_Float16*)alloc((size_t)nhid * nfeat * 2);
    _Float16*  y16    = (_Float16*)alloc((size_t)N * nhid * 2);   // layer-1 y
    _Float16*  h16    = (_Float16*)alloc((size_t)N * nhid * 2);   // relu output
    _Float16*  y2     = (_Float16*)alloc((size_t)N * nfeat * 2);  // layer-2 y
    float*     out    = (float*)d_out;
    (void)ws_size; (void)n_in; (void)out_size;

    const int T = 256;

    // ---- CSR build + dinv + weight prep ----
    k_zero2<<<(N + T - 1) / T, T, 0, stream>>>(deg_i, cursor, N);
    k_count<<<1024, T, 0, stream>>>(col, E, deg_i);
    k_scan1<<<nb, 1024, 0, stream>>>(deg_i, N, incl, bsum);
    k_scan2<<<1, 64, 0, stream>>>(bsum, boff, nb);
    k_scan3<<<(N + T - 1) / T, T, 0, stream>>>(incl, boff, deg_i, N, rowptr, dinv);
    k_fill<<<1024, T, 0, stream>>>(row, col, E, rowptr, cursor, srcidx);
    k_prep_w<<<(nhid * (nhid + nfeat) + T - 1) / T, T, 0, stream>>>(
        W1, W2, wt1, wt2, nhid, nhid, nfeat);

    // ---- layer 1 ----
    {
        dim3 grid(nhid / 128, (N + 127) / 128);
        k_gemm<true><<<grid, T, 0, stream>>>(x, nullptr, wt1, dinv, y16, N, nhid, nhid);
    }
    k_agg<32, true, true><<<(N + 3) / 4, T, 0, stream>>>(
        rowptr, srcidx, y16, dinv, b1, N, nullptr, h16);

    // ---- layer 2 ----
    {
        dim3 grid(nfeat / 128, (N + 127) / 128);
        k_gemm<false><<<grid, T, 0, stream>>>(nullptr, h16, wt2, dinv, y2, N, nhid, nfeat);
    }
    k_agg<16, false, false><<<(N + 3) / 4, T, 0, stream>>>(
        rowptr, srcidx, y2, dinv, b2, N, out, nullptr);
}